// Round 9
// baseline (135.743 us; speedup 1.0000x reference)
//
#include <hip/hip_runtime.h>

#define K_ELL 32      // ELL planes per near/far array (column-major)
#define K_OVF 16      // overflow planes (out-of-band fallback, expected empty)
#define TBS   1024    // build block size
#define RNG_LOG 12
#define RNG   4096    // build block a-range; RW = 8192 ints = 32 KB LDS
#define RW    (2 * RNG)
#define GW    1024    // gather vertices per block
#define GB    2048    // gather halo (covers ~1.7k band; global fallback if exceeded)
#define GWIN  (GW + 2 * GB)   // 5120 verts -> 3*5120*4 = 60 KB LDS
#define GBS   256

// prep: offs_a[u] = first edge index with edges[.].x >= u (edges[:,0] sorted asc,
// a<b, guaranteed by np.unique(np.sort(e,1),axis=0)); zero the few counters the
// build's LDS dumps don't cover; faces -> float copy.
__global__ void prep_kernel(const int2* __restrict__ edges, int* __restrict__ offs_a,
                            int* __restrict__ cntN, int* __restrict__ cntF,
                            int* __restrict__ deg_ovf,
                            const int* __restrict__ faces, float* __restrict__ out_f,
                            int E, int V, int F3) {
    int i = blockIdx.x * blockDim.x + threadIdx.x;
    if (i <= E) {
        if (i < E) {
            int lo = (i == 0) ? 0 : edges[i - 1].x + 1;
            int hi = edges[i].x;
            for (int a = lo; a <= hi; a++) offs_a[a] = i;
        } else {
            for (int a = edges[E - 1].x + 1; a <= V; a++) offs_a[a] = E;
        }
    }
    if (i < F3) out_f[i] = (float)faces[i];
    if (i < V) deg_ovf[i] = 0;
    if (i <= RNG) cntF[i] = 0;   // vertices with no far-owner block
    if (i == 0) cntN[0] = 0;     // vertex 0 has no near owner
}

// build: b-side transpose via LDS-rank atomics into column-major near/far ELL.
// Block b owns a-range [b*RNG, (b+1)*RNG); span comes from offs_a (no binary search).
// Near dump covers u in (v0, v0+RNG]; far dump covers u in (v0+RNG, v0+2*RNG].
__global__ __launch_bounds__(TBS) void build_kernel(
        const int2* __restrict__ edges, const int* __restrict__ offs_a,
        int* __restrict__ cntN, int* __restrict__ cntF, int* __restrict__ deg_ovf,
        int* __restrict__ adjN, int* __restrict__ adjF, int* __restrict__ adj_ovf,
        int E, int V) {
    __shared__ int cnt[RW];
    const int v0   = blockIdx.x << RNG_LOG;
    const int vEnd = min(v0 + RNG, V);
    for (int i = threadIdx.x; i < RW; i += TBS) cnt[i] = 0;
    const int eBeg = offs_a[v0];
    const int eEnd = offs_a[vEnd];
    __syncthreads();
    for (int i = eBeg + threadIdx.x; i < eEnd; i += TBS) {
        int2 e = edges[i];
        int rel = e.y - (v0 + 1);            // b > a >= v0 -> rel >= 0
        if (rel < RW) {
            int r = atomicAdd(&cnt[rel], 1); // LDS rank = final ELL slot
            if (rel < RNG) { if (r < K_ELL) adjN[(size_t)r * V + e.y] = e.x; }
            else           { if (r < K_ELL) adjF[(size_t)r * V + e.y] = e.x; }
        } else {                              // out-of-band fallback (rare/none)
            int r = atomicAdd(&deg_ovf[e.y], 1);
            if (r < K_OVF) adj_ovf[(size_t)r * V + e.y] = e.x;
        }
    }
    __syncthreads();
    for (int i = threadIdx.x; i < RW; i += TBS) {
        int u = v0 + 1 + i;
        if (u < V) {
            if (i < RNG) cntN[u] = cnt[i];
            else         cntF[u] = cnt[i];
        }
    }
}

// gather: one smoothing iteration (lambd==1 -> y = nbr_sum/deg; deg==0 -> 0).
// Stages x over [w0-GB, w0+GW+GB) into LDS (coalesced); neighbor reads become
// ds_read_b32. Out-of-window neighbors fall back to global loads.
__global__ __launch_bounds__(GBS) void gather_kernel(
        const float* __restrict__ x, const int2* __restrict__ edges,
        const int* __restrict__ offs_a,
        const int* __restrict__ cntN, const int* __restrict__ cntF,
        const int* __restrict__ deg_ovf,
        const int* __restrict__ adjN, const int* __restrict__ adjF,
        const int* __restrict__ adj_ovf,
        float* __restrict__ y, int V) {
    __shared__ float xs[GWIN], ys[GWIN], zs[GWIN];
    const int w0   = blockIdx.x * GW;
    const int wlo  = max(w0 - GB, 0);
    const int whi  = min(w0 + GW + GB, V);
    const int nwin = whi - wlo;
    const float* __restrict__ src = x + 3 * (size_t)wlo;
    for (int j = threadIdx.x; j < 3 * nwin; j += GBS) {
        float val = src[j];                  // fully coalesced streaming read
        int r = j / 3, c = j - 3 * r;
        if      (c == 0) xs[r] = val;
        else if (c == 1) ys[r] = val;
        else             zs[r] = val;
    }
    __syncthreads();
    for (int k = 0; k < GW / GBS; k++) {
        int u = w0 + k * GBS + threadIdx.x;
        if (u >= V) continue;
        int aBeg = offs_a[u], aEnd = offs_a[u + 1];
        int cN = cntN[u], cF = cntF[u], dO = deg_ovf[u];
        float s0 = 0.f, s1 = 0.f, s2 = 0.f;
        #define ACC(n) { int rel = (n) - wlo;                                        \
            if (rel >= 0 && rel < nwin) { s0 += xs[rel]; s1 += ys[rel]; s2 += zs[rel]; } \
            else { s0 += x[3*(n)]; s1 += x[3*(n)+1]; s2 += x[3*(n)+2]; } }
        for (int i = aBeg; i < aEnd; i++) { int n = edges[i].y; ACC(n); }
        int kN = cN > K_ELL ? K_ELL : cN;
        for (int j = 0; j < kN; j++) { int n = adjN[(size_t)j * V + u]; ACC(n); }
        int kF = cF > K_ELL ? K_ELL : cF;
        for (int j = 0; j < kF; j++) { int n = adjF[(size_t)j * V + u]; ACC(n); }
        int kO = dO > K_OVF ? K_OVF : dO;
        for (int j = 0; j < kO; j++) { int n = adj_ovf[(size_t)j * V + u]; ACC(n); }
        #undef ACC
        int d = (aEnd - aBeg) + cN + cF + dO;
        float inv = 1.0f / fmaxf((float)d, 1.0f);
        y[3 * u + 0] = s0 * inv;
        y[3 * u + 1] = s1 * inv;
        y[3 * u + 2] = s2 * inv;
    }
}

extern "C" void kernel_launch(void* const* d_in, const int* in_sizes, int n_in,
                              void* d_out, int out_size, void* d_ws, size_t ws_size,
                              hipStream_t stream) {
    const float* v     = (const float*)d_in[0];  // [V,3]
    const int2*  edges = (const int2*)d_in[1];   // [E,2], rows lex-sorted, a<b
    const int*   faces = (const int*)d_in[2];    // [F,3]

    const int V3 = in_sizes[0];
    const int V  = V3 / 3;
    const int E  = in_sizes[1] / 2;
    const int F3 = in_sizes[2];

    float* out_v = (float*)d_out;
    float* out_f = (float*)d_out + V3;

    // ws layout (4B words): adjN[K_ELL*V] | adjF[K_ELL*V] | adj_ovf[K_OVF*V] |
    //   offs_a[V+1] | cntN[V+1] | cntF[V+1] | deg_ovf[V] | x1[3V floats]
    int*   adjN    = (int*)d_ws;
    int*   adjF    = adjN + (size_t)K_ELL * V;
    int*   adj_ovf = adjF + (size_t)K_ELL * V;
    int*   offs_a  = adj_ovf + (size_t)K_OVF * V;
    int*   cntN    = offs_a + (V + 1);
    int*   cntF    = cntN + (V + 1);
    int*   deg_ovf = cntF + (V + 1);
    float* x1      = (float*)(deg_ovf + V + 3);  // keep 16B alignment

    const int NBb = (V + RNG - 1) / RNG;         // build blocks (~46)
    const int T1  = (E + 1) > F3 ? (E + 1) : F3; // prep covers edges+faces (+V zeroing)
    const int gP  = (T1 + 255) / 256;
    const int gG  = (V + GW - 1) / GW;           // gather blocks (~182)

    prep_kernel<<<gP, 256, 0, stream>>>(edges, offs_a, cntN, cntF, deg_ovf,
                                        faces, out_f, E, V, F3);

    build_kernel<<<NBb, TBS, 0, stream>>>(edges, offs_a, cntN, cntF, deg_ovf,
                                          adjN, adjF, adj_ovf, E, V);

    gather_kernel<<<gG, GBS, 0, stream>>>(v,  edges, offs_a, cntN, cntF, deg_ovf,
                                          adjN, adjF, adj_ovf, x1, V);
    gather_kernel<<<gG, GBS, 0, stream>>>(x1, edges, offs_a, cntN, cntF, deg_ovf,
                                          adjN, adjF, adj_ovf, out_v, V);
}

// Round 10
// 95.926 us; speedup vs baseline: 1.4151x; 1.4151x over previous
//
#include <hip/hip_runtime.h>

#define K_ELL 32      // ELL planes per near/far array (column-major; untouched planes = 0 traffic)
#define K_OVF 16      // overflow planes (out-of-band fallback, expected ~empty)
#define TBS   1024    // build block size
#define RNG_LOG 11
#define RNG   2048    // build block a-range
#define BAND  2048    // in-band limit on (b-a); == RNG so each vertex has unique far owner
#define RW    (RNG + BAND)   // 4096 ints = 16 KB LDS
#define BS    256

// prep: offs_a[u] = first edge index with edges[.].x >= u (edges[:,0] sorted asc, a<b,
// from np.unique(np.sort(e,1),axis=0)); faces -> float; v -> float4 repack; zero the
// counters build's LDS dumps don't cover (deg_ovf, cntF[0..RNG], cntN[0]).
__global__ void prep_kernel(const int2* __restrict__ edges, int* __restrict__ offs_a,
                            int* __restrict__ cntN, int* __restrict__ cntF,
                            int* __restrict__ deg_ovf,
                            const int* __restrict__ faces, float* __restrict__ out_f,
                            const float* __restrict__ v, float4* __restrict__ v4,
                            int E, int V, int F3) {
    int i = blockIdx.x * blockDim.x + threadIdx.x;
    if (i < F3) out_f[i] = (float)faces[i];
    if (i <= E) {
        if (i < E) {
            int lo = (i == 0) ? 0 : edges[i - 1].x + 1;
            int hi = edges[i].x;
            for (int a = lo; a <= hi; a++) offs_a[a] = i;
        } else {
            for (int a = edges[E - 1].x + 1; a <= V; a++) offs_a[a] = E;
        }
    }
    if (i < V) {
        v4[i] = make_float4(v[3 * i], v[3 * i + 1], v[3 * i + 2], 0.f);
        deg_ovf[i] = 0;
    }
    if (i <= RNG) cntF[i] = 0;   // vertices with no far-owner block
    if (i == 0) cntN[0] = 0;     // vertex 0 has no near-owner block
}

// build: b-side transpose via LDS-rank atomics into column-major near/far ELL.
// Block k owns a-range [k*RNG, (k+1)*RNG); edge span from offs_a (2 scalar loads).
// Near dump: u in (v0, v0+RNG]; far dump: u in (v0+RNG, v0+2*RNG] (unique owners).
__global__ __launch_bounds__(TBS) void build_kernel(
        const int2* __restrict__ edges, const int* __restrict__ offs_a,
        int* __restrict__ cntN, int* __restrict__ cntF, int* __restrict__ deg_ovf,
        int* __restrict__ adjN, int* __restrict__ adjF, int* __restrict__ adj_ovf,
        int E, int V) {
    __shared__ int cnt[RW];
    const int v0   = blockIdx.x << RNG_LOG;
    const int vEnd = min(v0 + RNG, V);
    for (int i = threadIdx.x; i < RW; i += TBS) cnt[i] = 0;
    const int eBeg = offs_a[v0];
    const int eEnd = offs_a[vEnd];
    __syncthreads();
    for (int i = eBeg + threadIdx.x; i < eEnd; i += TBS) {
        int2 e = edges[i];
        int rel = e.y - (v0 + 1);            // b > a >= v0 -> rel >= 0
        if (rel < RW) {
            int r = atomicAdd(&cnt[rel], 1); // LDS rank = final ELL slot
            if (rel < RNG) { if (r < K_ELL) adjN[(size_t)r * V + e.y] = e.x; }
            else           { if (r < K_ELL) adjF[(size_t)r * V + e.y] = e.x; }
        } else {                              // out-of-band fallback (rare; always correct)
            int r = atomicAdd(&deg_ovf[e.y], 1);
            if (r < K_OVF) adj_ovf[(size_t)r * V + e.y] = e.x;
        }
    }
    __syncthreads();
    for (int i = threadIdx.x; i < RW; i += TBS) {
        int u = v0 + 1 + i;
        if (u < V) {
            if (i < RNG) cntN[u] = cnt[i];
            else         cntF[u] = cnt[i];
        }
    }
}

// gather (R6 structure, unchanged occupancy): lambd==1 -> y = nbr_sum/deg (deg==0 -> 0).
template <bool PAD>
__global__ void gather_kernel(const float4* __restrict__ x4, const int2* __restrict__ edges,
                              const int* __restrict__ offs_a,
                              const int* __restrict__ cntN, const int* __restrict__ cntF,
                              const int* __restrict__ deg_ovf,
                              const int* __restrict__ adjN, const int* __restrict__ adjF,
                              const int* __restrict__ adj_ovf,
                              float* __restrict__ y, int V) {
    int u = blockIdx.x * blockDim.x + threadIdx.x;
    if (u >= V) return;
    int aBeg = offs_a[u], aEnd = offs_a[u + 1];
    int cN = cntN[u], cF = cntF[u], dO = deg_ovf[u];
    float s0 = 0.f, s1 = 0.f, s2 = 0.f;
    for (int i = aBeg; i < aEnd; i++) {
        float4 p = x4[edges[i].y];
        s0 += p.x; s1 += p.y; s2 += p.z;
    }
    int kN = cN > K_ELL ? K_ELL : cN;
    for (int k = 0; k < kN; k++) {
        float4 p = x4[adjN[(size_t)k * V + u]];   // coalesced plane reads
        s0 += p.x; s1 += p.y; s2 += p.z;
    }
    int kF = cF > K_ELL ? K_ELL : cF;
    for (int k = 0; k < kF; k++) {
        float4 p = x4[adjF[(size_t)k * V + u]];
        s0 += p.x; s1 += p.y; s2 += p.z;
    }
    int kO = dO > K_OVF ? K_OVF : dO;
    for (int k = 0; k < kO; k++) {                // expected empty
        float4 p = x4[adj_ovf[(size_t)k * V + u]];
        s0 += p.x; s1 += p.y; s2 += p.z;
    }
    int d = (aEnd - aBeg) + cN + cF + dO;
    float inv = 1.0f / fmaxf((float)d, 1.0f);
    if (PAD) {
        ((float4*)y)[u] = make_float4(s0 * inv, s1 * inv, s2 * inv, 0.f);
    } else {
        y[3 * u + 0] = s0 * inv;
        y[3 * u + 1] = s1 * inv;
        y[3 * u + 2] = s2 * inv;
    }
}

extern "C" void kernel_launch(void* const* d_in, const int* in_sizes, int n_in,
                              void* d_out, int out_size, void* d_ws, size_t ws_size,
                              hipStream_t stream) {
    const float* v     = (const float*)d_in[0];  // [V,3]
    const int2*  edges = (const int2*)d_in[1];   // [E,2], rows lex-sorted, a<b
    const int*   faces = (const int*)d_in[2];    // [F,3]

    const int V3 = in_sizes[0];
    const int V  = V3 / 3;
    const int E  = in_sizes[1] / 2;
    const int F3 = in_sizes[2];

    float* out_v = (float*)d_out;
    float* out_f = (float*)d_out + V3;

    // ws layout (16B-aligned float4 arrays first): v4[V] | x1[V] | adjN[K_ELL*V] |
    //   adjF[K_ELL*V] | adj_ovf[K_OVF*V] | offs_a[V+1] | cntN[V+1] | cntF[V+1] | deg_ovf[V]
    float4* v4      = (float4*)d_ws;
    float4* x1      = v4 + V;
    int*    adjN    = (int*)(x1 + V);
    int*    adjF    = adjN + (size_t)K_ELL * V;
    int*    adj_ovf = adjF + (size_t)K_ELL * V;
    int*    offs_a  = adj_ovf + (size_t)K_OVF * V;
    int*    cntN    = offs_a + (V + 1);
    int*    cntF    = cntN + (V + 1);
    int*    deg_ovf = cntF + (V + 1);

    const int NBb = (V + RNG - 1) / RNG;          // build blocks (~91)
    int prepN = F3 > (E + 1) ? F3 : (E + 1);
    if (V + 1 > prepN) prepN = V + 1;
    const int gP = (prepN + BS - 1) / BS;
    const int gV = (V + BS - 1) / BS;

    prep_kernel<<<gP, BS, 0, stream>>>(edges, offs_a, cntN, cntF, deg_ovf,
                                       faces, out_f, v, v4, E, V, F3);

    build_kernel<<<NBb, TBS, 0, stream>>>(edges, offs_a, cntN, cntF, deg_ovf,
                                          adjN, adjF, adj_ovf, E, V);

    gather_kernel<true ><<<gV, BS, 0, stream>>>(v4, edges, offs_a, cntN, cntF, deg_ovf,
                                                adjN, adjF, adj_ovf, (float*)x1, V);
    gather_kernel<false><<<gV, BS, 0, stream>>>(x1, edges, offs_a, cntN, cntF, deg_ovf,
                                                adjN, adjF, adj_ovf, out_v, V);
}

// Round 11
// 94.987 us; speedup vs baseline: 1.4291x; 1.0099x over previous
//
#include <hip/hip_runtime.h>

#define K_ELL 32      // ELL planes per near/far array (column-major; untouched planes = 0 traffic)
#define K_OVF 16      // overflow planes (out-of-band fallback, expected ~empty)
#define TBS   1024    // build block size
#define RNG_LOG 11
#define RNG   2048    // build block a-range
#define BAND  2048    // in-band limit on (b - v0 - 1); == RNG so each vertex has unique far owner
#define RW    (RNG + BAND)   // 4096 ints = 16 KB LDS
#define BS    256

// prep (light): offs_a[u] = first edge index with edges[.].x >= u (edges[:,0] sorted
// asc, a<b, from np.unique(np.sort(e,1),axis=0)); zero the counters build's LDS
// dumps don't cover (deg_ovf, cntF[0..RNG], cntN[0]).
__global__ void prep_kernel(const int2* __restrict__ edges, int* __restrict__ offs_a,
                            int* __restrict__ cntN, int* __restrict__ cntF,
                            int* __restrict__ deg_ovf, int E, int V) {
    int i = blockIdx.x * blockDim.x + threadIdx.x;
    if (i <= E) {
        if (i < E) {
            int lo = (i == 0) ? 0 : edges[i - 1].x + 1;
            int hi = edges[i].x;
            for (int a = lo; a <= hi; a++) offs_a[a] = i;
        } else {
            for (int a = edges[E - 1].x + 1; a <= V; a++) offs_a[a] = E;
        }
    }
    if (i < V) deg_ovf[i] = 0;
    if (i <= RNG) cntF[i] = 0;   // vertices with no far-owner block
    if (i == 0) cntN[0] = 0;     // vertex 0 has no near-owner block
}

// build: heavy blocks (< NBb) do the b-side transpose via LDS-rank atomics into
// column-major near/far ELL; copy blocks (>= NBb) do faces->float and v->float4
// on the ~165 CUs the 91 heavy blocks leave idle.
__global__ __launch_bounds__(TBS) void build_kernel(
        const int2* __restrict__ edges, const int* __restrict__ offs_a,
        int* __restrict__ cntN, int* __restrict__ cntF, int* __restrict__ deg_ovf,
        int* __restrict__ adjN, int* __restrict__ adjF, int* __restrict__ adj_ovf,
        const int* __restrict__ faces, float* __restrict__ out_f,
        const float* __restrict__ v, float4* __restrict__ v4,
        int E, int V, int F3, int NBb) {
    if ((int)blockIdx.x >= NBb) {
        int t = (blockIdx.x - NBb) * TBS + threadIdx.x;
        int T = (gridDim.x - NBb) * TBS;
        for (int j = t; j < F3; j += T) out_f[j] = (float)faces[j];
        for (int u = t; u < V; u += T)
            v4[u] = make_float4(v[3 * u], v[3 * u + 1], v[3 * u + 2], 0.f);
        return;
    }
    __shared__ int cnt[RW];
    const int v0   = blockIdx.x << RNG_LOG;
    const int vEnd = min(v0 + RNG, V);
    for (int i = threadIdx.x; i < RW; i += TBS) cnt[i] = 0;
    const int eBeg = offs_a[v0];
    const int eEnd = offs_a[vEnd];
    __syncthreads();
    for (int i = eBeg + threadIdx.x; i < eEnd; i += TBS) {
        int2 e = edges[i];
        int rel = e.y - (v0 + 1);            // b > a >= v0 -> rel >= 0
        if (rel < RW) {
            int r = atomicAdd(&cnt[rel], 1); // LDS rank = final ELL slot
            if (rel < RNG) { if (r < K_ELL) adjN[(size_t)r * V + e.y] = e.x; }
            else           { if (r < K_ELL) adjF[(size_t)r * V + e.y] = e.x; }
        } else {                              // out-of-band fallback (rare; always correct)
            int r = atomicAdd(&deg_ovf[e.y], 1);
            if (r < K_OVF) adj_ovf[(size_t)r * V + e.y] = e.x;
        }
    }
    __syncthreads();
    for (int i = threadIdx.x; i < RW; i += TBS) {
        int u = v0 + 1 + i;
        if (u < V) {
            if (i < RNG) cntN[u] = cnt[i];   // unique near owner
            else         cntF[u] = cnt[i];   // unique far owner (BAND == RNG)
        }
    }
}

// gather (R10 structure, unchanged): lambd==1 -> y = nbr_sum/deg (deg==0 -> 0, matches ref).
template <bool PAD>
__global__ void gather_kernel(const float4* __restrict__ x4, const int2* __restrict__ edges,
                              const int* __restrict__ offs_a,
                              const int* __restrict__ cntN, const int* __restrict__ cntF,
                              const int* __restrict__ deg_ovf,
                              const int* __restrict__ adjN, const int* __restrict__ adjF,
                              const int* __restrict__ adj_ovf,
                              float* __restrict__ y, int V) {
    int u = blockIdx.x * blockDim.x + threadIdx.x;
    if (u >= V) return;
    int aBeg = offs_a[u], aEnd = offs_a[u + 1];
    int cN = cntN[u], cF = cntF[u], dO = deg_ovf[u];
    float s0 = 0.f, s1 = 0.f, s2 = 0.f;
    for (int i = aBeg; i < aEnd; i++) {
        float4 p = x4[edges[i].y];
        s0 += p.x; s1 += p.y; s2 += p.z;
    }
    int kN = cN > K_ELL ? K_ELL : cN;
    for (int k = 0; k < kN; k++) {
        float4 p = x4[adjN[(size_t)k * V + u]];   // coalesced plane reads
        s0 += p.x; s1 += p.y; s2 += p.z;
    }
    int kF = cF > K_ELL ? K_ELL : cF;
    for (int k = 0; k < kF; k++) {
        float4 p = x4[adjF[(size_t)k * V + u]];
        s0 += p.x; s1 += p.y; s2 += p.z;
    }
    int kO = dO > K_OVF ? K_OVF : dO;
    for (int k = 0; k < kO; k++) {                // expected empty
        float4 p = x4[adj_ovf[(size_t)k * V + u]];
        s0 += p.x; s1 += p.y; s2 += p.z;
    }
    int d = (aEnd - aBeg) + cN + cF + dO;
    float inv = 1.0f / fmaxf((float)d, 1.0f);
    if (PAD) {
        ((float4*)y)[u] = make_float4(s0 * inv, s1 * inv, s2 * inv, 0.f);
    } else {
        y[3 * u + 0] = s0 * inv;
        y[3 * u + 1] = s1 * inv;
        y[3 * u + 2] = s2 * inv;
    }
}

extern "C" void kernel_launch(void* const* d_in, const int* in_sizes, int n_in,
                              void* d_out, int out_size, void* d_ws, size_t ws_size,
                              hipStream_t stream) {
    const float* v     = (const float*)d_in[0];  // [V,3]
    const int2*  edges = (const int2*)d_in[1];   // [E,2], rows lex-sorted, a<b
    const int*   faces = (const int*)d_in[2];    // [F,3]

    const int V3 = in_sizes[0];
    const int V  = V3 / 3;
    const int E  = in_sizes[1] / 2;
    const int F3 = in_sizes[2];

    float* out_v = (float*)d_out;
    float* out_f = (float*)d_out + V3;

    // ws layout (16B-aligned float4 arrays first): v4[V] | x1[V] | adjN[K_ELL*V] |
    //   adjF[K_ELL*V] | adj_ovf[K_OVF*V] | offs_a[V+1] | cntN[V+1] | cntF[V+1] | deg_ovf[V]
    float4* v4      = (float4*)d_ws;
    float4* x1      = v4 + V;
    int*    adjN    = (int*)(x1 + V);
    int*    adjF    = adjN + (size_t)K_ELL * V;
    int*    adj_ovf = adjF + (size_t)K_ELL * V;
    int*    offs_a  = adj_ovf + (size_t)K_OVF * V;
    int*    cntN    = offs_a + (V + 1);
    int*    cntF    = cntN + (V + 1);
    int*    deg_ovf = cntF + (V + 1);

    const int NBb = (V + RNG - 1) / RNG;          // heavy build blocks (~91)
    const int copyElems = F3 > V ? F3 : V;
    const int NBc = (copyElems + TBS - 1) / TBS;  // copy blocks (~1086)
    const int gP  = (E + 1 + BS - 1) / BS;        // prep covers edges (+V zeroing folded)
    const int gV  = (V + BS - 1) / BS;

    prep_kernel<<<gP, BS, 0, stream>>>(edges, offs_a, cntN, cntF, deg_ovf, E, V);

    build_kernel<<<NBb + NBc, TBS, 0, stream>>>(edges, offs_a, cntN, cntF, deg_ovf,
                                                adjN, adjF, adj_ovf, faces, out_f,
                                                v, v4, E, V, F3, NBb);

    gather_kernel<true ><<<gV, BS, 0, stream>>>(v4, edges, offs_a, cntN, cntF, deg_ovf,
                                                adjN, adjF, adj_ovf, (float*)x1, V);
    gather_kernel<false><<<gV, BS, 0, stream>>>(x1, edges, offs_a, cntN, cntF, deg_ovf,
                                                adjN, adjF, adj_ovf, out_v, V);
}